// Round 5
// baseline (588.045 us; speedup 1.0000x reference)
//
#include <hip/hip_runtime.h>
#include <hip/hip_bf16.h>

// ---------------------------------------------------------------------------
// GraphChebNet: 3-layer ChebConv (K=2), N=50000, E=400000.
// Round 5: fuse gather into GEMM. Each 64-row block gathers its nodes' T-rows
// (A_hat @ H) into LDS Ts[64][K+8] (fp32 reg accumulate -> bf16 LDS, same
// numerics as the old txb path), then the MFMA pass-1 reads A-fragments from
// Ts. Kills the tx HBM round-trip (153 MB) and the gather->GEMM grid barrier.
// CSR build: dinv merged into scan_partial, cursor written by scan_chunk
// (memcpy dropped). 11 dispatches total.
// ---------------------------------------------------------------------------

typedef __attribute__((ext_vector_type(8))) short bf16x8;
typedef __attribute__((ext_vector_type(4))) float f32x4;

__device__ __forceinline__ float bf2f(unsigned int lo16) {
    unsigned int t = lo16 << 16;
    return __builtin_bit_cast(float, t);
}
__device__ __forceinline__ unsigned short f2bf(float f) {
    unsigned int u = __builtin_bit_cast(unsigned int, f);
    unsigned int r = (u + 0x7fffu + ((u >> 16) & 1u)) >> 16;   // RNE
    return (unsigned short)r;
}

// ---------------- norm + CSR build ----------------
__global__ __launch_bounds__(256) void deg_cnt_kernel(const int* __restrict__ src,
                                                      const int* __restrict__ dst,
                                                      float* __restrict__ deg,
                                                      int* __restrict__ cnt, int E) {
    int e = blockIdx.x * blockDim.x + threadIdx.x;
    if (e < E) {
        int s = src[e], d = dst[e];
        if (s != d) atomicAdd(&deg[s], 1.0f);
        atomicAdd(&cnt[d], 1);
    }
}

// partial sums for the scan AND deg -> dinv in place (independent data)
__global__ __launch_bounds__(256) void scan_partial_dinv(const int* __restrict__ cnt,
                                                         int* __restrict__ part,
                                                         float* __restrict__ deg, int N) {
    __shared__ int lds[256];
    int tid = threadIdx.x;
    int base = blockIdx.x * 1024 + tid * 4;
    int s = 0;
    #pragma unroll
    for (int i = 0; i < 4; ++i) {
        if (base + i < N) {
            s += cnt[base + i];
            float d = deg[base + i];
            deg[base + i] = (d > 0.0f) ? rsqrtf(d) : 0.0f;
        }
    }
    lds[tid] = s;
    __syncthreads();
    for (int off = 128; off > 0; off >>= 1) {
        if (tid < off) lds[tid] += lds[tid + off];
        __syncthreads();
    }
    if (tid == 0) part[blockIdx.x] = lds[0];
}

__global__ __launch_bounds__(64) void scan_small(int* __restrict__ part, int NB,
                                                 int* __restrict__ rowptr, int N) {
    if (threadIdx.x == 0 && blockIdx.x == 0) {
        int total = 0;
        for (int i = 0; i < NB; ++i) { int t = part[i]; part[i] = total; total += t; }
        rowptr[N] = total;
    }
}

__global__ __launch_bounds__(256) void scan_chunk(const int* __restrict__ cnt,
                                                  const int* __restrict__ part,
                                                  int* __restrict__ rowptr,
                                                  int* __restrict__ cursor, int N) {
    __shared__ int lds[256];
    int tid = threadIdx.x;
    int base = blockIdx.x * 1024 + tid * 4;
    int c[4];
    #pragma unroll
    for (int i = 0; i < 4; ++i) c[i] = (base + i < N) ? cnt[base + i] : 0;
    int ts = c[0] + c[1] + c[2] + c[3];
    lds[tid] = ts;
    __syncthreads();
    for (int off = 1; off < 256; off <<= 1) {
        int v = (tid >= off) ? lds[tid - off] : 0;
        __syncthreads();
        lds[tid] += v;
        __syncthreads();
    }
    int o = part[blockIdx.x] + lds[tid] - ts;
    #pragma unroll
    for (int i = 0; i < 4; ++i) {
        if (base + i < N) { rowptr[base + i] = o; cursor[base + i] = o; }
        o += c[i];
    }
}

__global__ __launch_bounds__(256) void fill_kernel(const int* __restrict__ src,
                                                   const int* __restrict__ dst,
                                                   const float* __restrict__ dinv,
                                                   int* __restrict__ cursor,
                                                   int* __restrict__ esrc,
                                                   float* __restrict__ ew, int E) {
    int e = blockIdx.x * blockDim.x + threadIdx.x;
    if (e < E) {
        int s = src[e], d = dst[e];
        int pos = atomicAdd(&cursor[d], 1);
        esrc[pos] = s;
        ew[pos] = (s != d) ? (-dinv[s] * dinv[d]) : 0.0f;
    }
}

// ---------------- prep: casts ----------------
__global__ __launch_bounds__(256) void cast_x_kernel(const float* __restrict__ x,
                                                     unsigned short* __restrict__ xb,
                                                     long long n4) {
    long long i = (long long)blockIdx.x * 256 + threadIdx.x;
    if (i >= n4) return;
    float4 v = reinterpret_cast<const float4*>(x)[i];
    ushort4 o;
    o.x = f2bf(v.x); o.y = f2bf(v.y); o.z = f2bf(v.z); o.w = f2bf(v.w);
    reinterpret_cast<ushort4*>(xb)[i] = o;
}

struct TParams {
    const float* W[6];
    unsigned short* WT[6];
    int K[6];
};
__global__ __launch_bounds__(256) void transpose_cast_all(TParams p) {
    int m = blockIdx.z;
    int K = p.K[m];
    int kb = blockIdx.x * 32, nb = blockIdx.y * 32;
    if (kb >= K) return;
    const float* W = p.W[m];
    unsigned short* WT = p.WT[m];
    __shared__ float t[32][33];
    int lx = threadIdx.x & 31, ly = threadIdx.x >> 5;
    #pragma unroll
    for (int i = 0; i < 32; i += 8)
        t[ly + i][lx] = W[(size_t)(kb + ly + i) * 256 + nb + lx];
    __syncthreads();
    #pragma unroll
    for (int i = 0; i < 32; i += 8)
        WT[(size_t)(nb + ly + i) * K + kb + lx] = f2bf(t[lx][ly + i]);
}

// ---------------- fused layer: gather + dual-GEMM + bias/relu ----------------
// out[M,256] = relu?( Hb@W0 + (A_hat Hb)@W1 + b ), weights as WT[n][k] bf16.
// Block = 64 rows x 256 cols, 256 threads = 4 waves. Prologue: wave w gathers
// T-rows for nodes [row0+16w, row0+16w+16) into Ts (fp32 acc -> bf16).
// Pass 0: A-frags from staged As (Hb). Pass 1: A-frags straight from Ts.
template <int K, bool RELU, typename OutT>
__global__ __launch_bounds__(256, 2) void layer_fused(const unsigned short* __restrict__ Hb,
                                                      const int* __restrict__ rowptr,
                                                      const int* __restrict__ esrc,
                                                      const float* __restrict__ ew,
                                                      const unsigned short* __restrict__ W0T,
                                                      const unsigned short* __restrict__ W1T,
                                                      const float* __restrict__ bias,
                                                      OutT* __restrict__ out, int M) {
    constexpr int SA = 72;        // staging stride (shorts): 2-way alias = free
    constexpr int TSS = K + 8;    // Ts stride
    __shared__ unsigned short Ts[64 * TSS];
    __shared__ unsigned short As[64 * SA];
    __shared__ unsigned short Bs[256 * SA];

    const int tid = threadIdx.x;
    const int wave = tid >> 6;
    const int lane = tid & 63;
    const int l15 = lane & 15;
    const int quad = lane >> 4;
    const int row0 = blockIdx.x * 64;

    // ---- prologue: gather ----
    constexpr int V = K / 64;     // bf16 per lane (2 or 4)
    for (int i = 0; i < 16; ++i) {
        int nl = wave * 16 + i;
        int gn = row0 + nl;
        int beg = 0, end = 0;
        if (gn < M) { beg = rowptr[gn]; end = rowptr[gn + 1]; }
        float acc[V] = {};
        int s_next = 0; float w_next = 0.0f;
        if (beg < end) { s_next = esrc[beg]; w_next = ew[beg]; }
        for (int k = beg; k < end; ++k) {
            int s = s_next; float wv = w_next;
            if (k + 1 < end) { s_next = esrc[k + 1]; w_next = ew[k + 1]; }
            const unsigned short* p = &Hb[(size_t)s * K + lane * V];
            if (V == 2) {
                unsigned int u = *reinterpret_cast<const unsigned int*>(p);
                acc[0] += wv * bf2f(u & 0xffffu);
                acc[1] += wv * bf2f(u >> 16);
            } else {
                uint2 u = *reinterpret_cast<const uint2*>(p);
                acc[0] += wv * bf2f(u.x & 0xffffu);
                acc[1] += wv * bf2f(u.x >> 16);
                acc[2] += wv * bf2f(u.y & 0xffffu);
                acc[3] += wv * bf2f(u.y >> 16);
            }
        }
        unsigned short* q = &Ts[nl * TSS + lane * V];
        if (V == 2) {
            unsigned int o = (unsigned int)f2bf(acc[0]) | ((unsigned int)f2bf(acc[1]) << 16);
            *reinterpret_cast<unsigned int*>(q) = o;
        } else {
            uint2 o;
            o.x = (unsigned int)f2bf(acc[0]) | ((unsigned int)f2bf(acc[1]) << 16);
            o.y = (unsigned int)f2bf(acc[2]) | ((unsigned int)f2bf(acc[3]) << 16);
            *reinterpret_cast<uint2*>(q) = o;
        }
    }
    // Ts-write -> Ts-read (pass 1) ordering is provided by pass 0's barriers.

    // ---- MFMA main loop ----
    const int srow = tid >> 3;          // 0..31 per staging round
    const int scol = (tid & 7) * 8;     // 0..56

    f32x4 acc4[4][4];
    #pragma unroll
    for (int i = 0; i < 4; ++i)
        #pragma unroll
        for (int j = 0; j < 4; ++j) acc4[i][j] = (f32x4){0.f, 0.f, 0.f, 0.f};

    #pragma unroll
    for (int pass = 0; pass < 2; ++pass) {
        const unsigned short* Wmat = pass ? W1T : W0T;
        for (int k0 = 0; k0 < K; k0 += 64) {
            if (pass != 0 || k0 != 0) __syncthreads();
            if (pass == 0) {
                #pragma unroll
                for (int r = 0; r < 2; ++r) {
                    int row = r * 32 + srow;
                    int grow = row0 + row; if (grow > M - 1) grow = M - 1;
                    uint4 v = *reinterpret_cast<const uint4*>(&Hb[(size_t)grow * K + k0 + scol]);
                    *reinterpret_cast<uint4*>(&As[row * SA + scol]) = v;
                }
            }
            #pragma unroll
            for (int r = 0; r < 8; ++r) {
                int row = r * 32 + srow;
                uint4 v = *reinterpret_cast<const uint4*>(&Wmat[(size_t)row * K + k0 + scol]);
                *reinterpret_cast<uint4*>(&Bs[row * SA + scol]) = v;
            }
            __syncthreads();

            #pragma unroll
            for (int kf = 0; kf < 2; ++kf) {
                const int koff = kf * 32 + quad * 8;
                bf16x8 a[4], b[4];
                #pragma unroll
                for (int mt = 0; mt < 4; ++mt) {
                    if (pass == 0)
                        a[mt] = *reinterpret_cast<const bf16x8*>(&As[(mt * 16 + l15) * SA + koff]);
                    else
                        a[mt] = *reinterpret_cast<const bf16x8*>(&Ts[(mt * 16 + l15) * TSS + k0 + koff]);
                }
                #pragma unroll
                for (int nt = 0; nt < 4; ++nt)
                    b[nt] = *reinterpret_cast<const bf16x8*>(
                        &Bs[(wave * 64 + nt * 16 + l15) * SA + koff]);
                #pragma unroll
                for (int mt = 0; mt < 4; ++mt)
                    #pragma unroll
                    for (int nt = 0; nt < 4; ++nt)
                        acc4[mt][nt] = __builtin_amdgcn_mfma_f32_16x16x32_bf16(
                            a[mt], b[nt], acc4[mt][nt], 0, 0, 0);
            }
        }
    }

    // epilogue: C/D layout col=lane&15, row=quad*4+reg
    #pragma unroll
    for (int mt = 0; mt < 4; ++mt) {
        #pragma unroll
        for (int r = 0; r < 4; ++r) {
            int m = row0 + mt * 16 + quad * 4 + r;
            if (m >= M) continue;
            #pragma unroll
            for (int nt = 0; nt < 4; ++nt) {
                int n = wave * 64 + nt * 16 + l15;
                float v = acc4[mt][nt][r] + bias[n];
                if (RELU) v = fmaxf(v, 0.0f);
                if constexpr (sizeof(OutT) == 2)
                    out[(size_t)m * 256 + n] = (OutT)f2bf(v);
                else
                    out[(size_t)m * 256 + n] = (OutT)v;
            }
        }
    }
}

static inline size_t align_up(size_t v, size_t a) { return (v + a - 1) / a * a; }

extern "C" void kernel_launch(void* const* d_in, const int* in_sizes, int n_in,
                              void* d_out, int out_size, void* d_ws, size_t ws_size,
                              hipStream_t stream) {
    const float* x    = (const float*)d_in[0];
    const int*   ei   = (const int*)d_in[1];
    const float* W1_0 = (const float*)d_in[2];
    const float* W1_1 = (const float*)d_in[3];
    const float* b1   = (const float*)d_in[4];
    const float* W2_0 = (const float*)d_in[5];
    const float* W2_1 = (const float*)d_in[6];
    const float* b2   = (const float*)d_in[7];
    const float* W3_0 = (const float*)d_in[8];
    const float* W3_1 = (const float*)d_in[9];
    const float* b3   = (const float*)d_in[10];
    float* out = (float*)d_out;

    const int N = in_sizes[0] / 128;
    const int E = in_sizes[1] / 2;
    const int* src = ei;
    const int* dst = ei + E;

    typedef unsigned short u16;
    char* ws = (char*)d_ws;
    size_t off = 0;
    float* dinv   = (float*)(ws + off); off = align_up(off + (size_t)N * 4, 256);
    int*   cnt    = (int*)  (ws + off); off = align_up(off + (size_t)N * 4, 256);
    size_t zero_end = off;
    int*   rowptr = (int*)  (ws + off); off = align_up(off + (size_t)(N + 1) * 4, 256);
    int*   cursor = (int*)  (ws + off); off = align_up(off + (size_t)N * 4, 256);
    int*   part   = (int*)  (ws + off); off = align_up(off + 256 * 4, 256);
    int*   esrc   = (int*)  (ws + off); off = align_up(off + (size_t)E * 4, 256);
    float* ew     = (float*)(ws + off); off = align_up(off + (size_t)E * 4, 256);
    u16*   xb     = (u16*)  (ws + off); off = align_up(off + (size_t)N * 128 * 2, 256);
    u16*   h1b    = (u16*)  (ws + off); off = align_up(off + (size_t)N * 256 * 2, 256);
    u16*   h2b    = (u16*)  (ws + off); off = align_up(off + (size_t)N * 256 * 2, 256);
    u16*   W10T   = (u16*)  (ws + off); off = align_up(off + (size_t)256 * 128 * 2, 256);
    u16*   W11T   = (u16*)  (ws + off); off = align_up(off + (size_t)256 * 128 * 2, 256);
    u16*   W20T   = (u16*)  (ws + off); off = align_up(off + (size_t)256 * 256 * 2, 256);
    u16*   W21T   = (u16*)  (ws + off); off = align_up(off + (size_t)256 * 256 * 2, 256);
    u16*   W30T   = (u16*)  (ws + off); off = align_up(off + (size_t)256 * 256 * 2, 256);
    u16*   W31T   = (u16*)  (ws + off); off = align_up(off + (size_t)256 * 256 * 2, 256);
    (void)ws_size;

    const int TB = 256;
    dim3 gE((E + TB - 1) / TB);
    const int NB = (N + 1023) / 1024;

    // ---- norm + CSR build ----
    hipMemsetAsync(dinv, 0, zero_end, stream);
    deg_cnt_kernel<<<gE, TB, 0, stream>>>(src, dst, dinv, cnt, E);
    scan_partial_dinv<<<NB, 256, 0, stream>>>(cnt, part, dinv, N);
    scan_small<<<1, 64, 0, stream>>>(part, NB, rowptr, N);
    scan_chunk<<<NB, 256, 0, stream>>>(cnt, part, rowptr, cursor, N);
    fill_kernel<<<gE, TB, 0, stream>>>(src, dst, dinv, cursor, esrc, ew, E);

    // ---- prep casts ----
    {
        long long n4 = (long long)N * 128 / 4;
        cast_x_kernel<<<(unsigned)((n4 + 255) / 256), TB, 0, stream>>>(x, xb, n4);
    }
    {
        TParams p;
        p.W[0] = W1_0; p.WT[0] = W10T; p.K[0] = 128;
        p.W[1] = W1_1; p.WT[1] = W11T; p.K[1] = 128;
        p.W[2] = W2_0; p.WT[2] = W20T; p.K[2] = 256;
        p.W[3] = W2_1; p.WT[3] = W21T; p.K[3] = 256;
        p.W[4] = W3_0; p.WT[4] = W30T; p.K[4] = 256;
        p.W[5] = W3_1; p.WT[5] = W31T; p.K[5] = 256;
        transpose_cast_all<<<dim3(8, 8, 6), TB, 0, stream>>>(p);
    }

    dim3 grid((N + 63) / 64);

    // ---- fused layers ----
    layer_fused<128, true, u16><<<grid, TB, 0, stream>>>(xb, rowptr, esrc, ew,
                                                         W10T, W11T, b1, h1b, N);
    layer_fused<256, true, u16><<<grid, TB, 0, stream>>>(h1b, rowptr, esrc, ew,
                                                         W20T, W21T, b2, h2b, N);
    layer_fused<256, false, float><<<grid, TB, 0, stream>>>(h2b, rowptr, esrc, ew,
                                                            W30T, W31T, b3, out, N);
}

// Round 7
// 353.440 us; speedup vs baseline: 1.6638x; 1.6638x over previous
//
#include <hip/hip_runtime.h>
#include <hip/hip_bf16.h>

// ---------------------------------------------------------------------------
// GraphChebNet: 3-layer ChebConv (K=2), N=50000, E=400000.
// Round 7: round-6 structure (split gather x4-unrolled + BN=256 MFMA GEMM,
// 354us initial) with the cross-XCD hazard removed: round-5/6 wrote `cursor`
// with plain stores then cross-XCD atomicAdd-RMW'd it in fill_kernel (plain
// dirty L2 lines are NOT guaranteed visible to memory-side atomics -> stale
// cursor -> wrong CSR slots, intermittent post-timing divergence in round 6).
// Now: fill uses pos = rowptr[d] + atomicAdd(&cnt2[d],1) with cnt2 zeroed by
// hipMemsetAsync (SDMA, memory-side visible — proven-safe init path).
// ---------------------------------------------------------------------------

typedef __attribute__((ext_vector_type(8))) short bf16x8;
typedef __attribute__((ext_vector_type(4))) float f32x4;

__device__ __forceinline__ float bf2f(unsigned int lo16) {
    unsigned int t = lo16 << 16;
    return __builtin_bit_cast(float, t);
}
__device__ __forceinline__ unsigned short f2bf(float f) {
    unsigned int u = __builtin_bit_cast(unsigned int, f);
    unsigned int r = (u + 0x7fffu + ((u >> 16) & 1u)) >> 16;   // RNE
    return (unsigned short)r;
}

// ---------------- norm + CSR build ----------------
__global__ __launch_bounds__(256) void deg_cnt_kernel(const int* __restrict__ src,
                                                      const int* __restrict__ dst,
                                                      float* __restrict__ deg,
                                                      int* __restrict__ cnt, int E) {
    int e = blockIdx.x * blockDim.x + threadIdx.x;
    if (e < E) {
        int s = src[e], d = dst[e];
        if (s != d) atomicAdd(&deg[s], 1.0f);
        atomicAdd(&cnt[d], 1);
    }
}

// scan partial sums AND deg -> dinv in place (independent data, one pass)
__global__ __launch_bounds__(256) void scan_partial_dinv(const int* __restrict__ cnt,
                                                         int* __restrict__ part,
                                                         float* __restrict__ deg, int N) {
    __shared__ int lds[256];
    int tid = threadIdx.x;
    int base = blockIdx.x * 1024 + tid * 4;
    int s = 0;
    #pragma unroll
    for (int i = 0; i < 4; ++i) {
        if (base + i < N) {
            s += cnt[base + i];
            float d = deg[base + i];
            deg[base + i] = (d > 0.0f) ? rsqrtf(d) : 0.0f;
        }
    }
    lds[tid] = s;
    __syncthreads();
    for (int off = 128; off > 0; off >>= 1) {
        if (tid < off) lds[tid] += lds[tid + off];
        __syncthreads();
    }
    if (tid == 0) part[blockIdx.x] = lds[0];
}

__global__ __launch_bounds__(64) void scan_small(int* __restrict__ part, int NB,
                                                 int* __restrict__ rowptr, int N) {
    if (threadIdx.x == 0 && blockIdx.x == 0) {
        int total = 0;
        for (int i = 0; i < NB; ++i) { int t = part[i]; part[i] = total; total += t; }
        rowptr[N] = total;
    }
}

__global__ __launch_bounds__(256) void scan_chunk(const int* __restrict__ cnt,
                                                  const int* __restrict__ part,
                                                  int* __restrict__ rowptr, int N) {
    __shared__ int lds[256];
    int tid = threadIdx.x;
    int base = blockIdx.x * 1024 + tid * 4;
    int c[4];
    #pragma unroll
    for (int i = 0; i < 4; ++i) c[i] = (base + i < N) ? cnt[base + i] : 0;
    int ts = c[0] + c[1] + c[2] + c[3];
    lds[tid] = ts;
    __syncthreads();
    for (int off = 1; off < 256; off <<= 1) {
        int v = (tid >= off) ? lds[tid - off] : 0;
        __syncthreads();
        lds[tid] += v;
        __syncthreads();
    }
    int o = part[blockIdx.x] + lds[tid] - ts;
    #pragma unroll
    for (int i = 0; i < 4; ++i) {
        if (base + i < N) rowptr[base + i] = o;
        o += c[i];
    }
}

// CSR fill: slot = rowptr[d] (plain read, plain-written by scan_chunk) +
// atomic rank from cnt2 (memset-0 by SDMA -> safe for memory-side atomics).
__global__ __launch_bounds__(256) void fill_kernel(const int* __restrict__ src,
                                                   const int* __restrict__ dst,
                                                   const float* __restrict__ dinv,
                                                   const int* __restrict__ rowptr,
                                                   int* __restrict__ cnt2,
                                                   int* __restrict__ esrc,
                                                   float* __restrict__ ew, int E) {
    int e = blockIdx.x * blockDim.x + threadIdx.x;
    if (e < E) {
        int s = src[e], d = dst[e];
        int pos = rowptr[d] + atomicAdd(&cnt2[d], 1);
        esrc[pos] = s;
        ew[pos] = (s != d) ? (-dinv[s] * dinv[d]) : 0.0f;
    }
}

// ---------------- prep: casts ----------------
__global__ __launch_bounds__(256) void cast_x_kernel(const float* __restrict__ x,
                                                     unsigned short* __restrict__ xb,
                                                     long long n4) {
    long long i = (long long)blockIdx.x * 256 + threadIdx.x;
    if (i >= n4) return;
    float4 v = reinterpret_cast<const float4*>(x)[i];
    ushort4 o;
    o.x = f2bf(v.x); o.y = f2bf(v.y); o.z = f2bf(v.z); o.w = f2bf(v.w);
    reinterpret_cast<ushort4*>(xb)[i] = o;
}

struct TParams {
    const float* W[6];
    unsigned short* WT[6];
    int K[6];
};
__global__ __launch_bounds__(256) void transpose_cast_all(TParams p) {
    int m = blockIdx.z;
    int K = p.K[m];
    int kb = blockIdx.x * 32, nb = blockIdx.y * 32;
    if (kb >= K) return;
    const float* W = p.W[m];
    unsigned short* WT = p.WT[m];
    __shared__ float t[32][33];
    int lx = threadIdx.x & 31, ly = threadIdx.x >> 5;
    #pragma unroll
    for (int i = 0; i < 32; i += 8)
        t[ly + i][lx] = W[(size_t)(kb + ly + i) * 256 + nb + lx];
    __syncthreads();
    #pragma unroll
    for (int i = 0; i < 32; i += 8)
        WT[(size_t)(nb + ly + i) * K + kb + lx] = f2bf(t[lx][ly + i]);
}

// ---------------- gather: tx[n,:] = sum_e w_e * x[src_e,:], bf16 ----------------
// one wave per node; lane holds V=F/64 features; edge loop unrolled x4 (4
// independent row loads in flight). Bit-identical summation order to the
// round-4 1-deep version.
template <int V> struct RowT;
template <> struct RowT<2> { using T = unsigned int; };
template <> struct RowT<4> { using T = uint2; };

__device__ __forceinline__ void fma_row(float* acc, unsigned int u, float wv) {
    acc[0] += wv * bf2f(u & 0xffffu);
    acc[1] += wv * bf2f(u >> 16);
}
__device__ __forceinline__ void fma_row(float* acc, uint2 u, float wv) {
    acc[0] += wv * bf2f(u.x & 0xffffu);
    acc[1] += wv * bf2f(u.x >> 16);
    acc[2] += wv * bf2f(u.y & 0xffffu);
    acc[3] += wv * bf2f(u.y >> 16);
}

template <int F>
__global__ __launch_bounds__(256) void gather_bf16(const int* __restrict__ rowptr,
                                                   const int* __restrict__ esrc,
                                                   const float* __restrict__ ew,
                                                   const unsigned short* __restrict__ xb,
                                                   unsigned short* __restrict__ txb,
                                                   int N) {
    constexpr int V = F / 64;   // 2 or 4
    using T = typename RowT<V>::T;
    int wave = threadIdx.x >> 6, lane = threadIdx.x & 63;
    int n = blockIdx.x * 4 + wave;
    if (n >= N) return;
    int beg = rowptr[n], end = rowptr[n + 1];
    float acc[V] = {};

    int k = beg;
    for (; k + 4 <= end; k += 4) {
        int s0 = esrc[k], s1 = esrc[k + 1], s2 = esrc[k + 2], s3 = esrc[k + 3];
        float w0 = ew[k], w1 = ew[k + 1], w2 = ew[k + 2], w3 = ew[k + 3];
        T r0 = *reinterpret_cast<const T*>(&xb[(size_t)s0 * F + lane * V]);
        T r1 = *reinterpret_cast<const T*>(&xb[(size_t)s1 * F + lane * V]);
        T r2 = *reinterpret_cast<const T*>(&xb[(size_t)s2 * F + lane * V]);
        T r3 = *reinterpret_cast<const T*>(&xb[(size_t)s3 * F + lane * V]);
        fma_row(acc, r0, w0);
        fma_row(acc, r1, w1);
        fma_row(acc, r2, w2);
        fma_row(acc, r3, w3);
    }
    for (; k < end; ++k) {
        int s = esrc[k];
        float wv = ew[k];
        T r = *reinterpret_cast<const T*>(&xb[(size_t)s * F + lane * V]);
        fma_row(acc, r, wv);
    }

    unsigned short* q = &txb[(size_t)n * F + lane * V];
    if (V == 2) {
        unsigned int o = (unsigned int)f2bf(acc[0]) | ((unsigned int)f2bf(acc[1]) << 16);
        *reinterpret_cast<unsigned int*>(q) = o;
    } else {
        uint2 o;
        o.x = (unsigned int)f2bf(acc[0]) | ((unsigned int)f2bf(acc[1]) << 16);
        o.y = (unsigned int)f2bf(acc[2]) | ((unsigned int)f2bf(acc[3]) << 16);
        *reinterpret_cast<uint2*>(q) = o;
    }
}

// ---------------- MFMA GEMM, BN=256 (round-4, known good) ----------------
template <int K, bool RELU, typename OutT>
__global__ __launch_bounds__(256, 3) void gemm_mfma(const unsigned short* __restrict__ Xb,
                                                    const unsigned short* __restrict__ Tb,
                                                    const unsigned short* __restrict__ W0T,
                                                    const unsigned short* __restrict__ W1T,
                                                    const float* __restrict__ bias,
                                                    OutT* __restrict__ out, int M) {
    constexpr int SA = 72;   // LDS row stride (shorts): 2-way bank alias = free
    __shared__ unsigned short As[64 * SA];
    __shared__ unsigned short Bs[256 * SA];

    const int tid = threadIdx.x;
    const int wave = tid >> 6;
    const int lane = tid & 63;
    const int l15 = lane & 15;
    const int quad = lane >> 4;
    const int row0 = blockIdx.x * 64;

    const int srow = tid >> 3;          // 0..31 per staging round
    const int scol = (tid & 7) * 8;     // 0..56

    f32x4 acc[4][4];
    #pragma unroll
    for (int i = 0; i < 4; ++i)
        #pragma unroll
        for (int j = 0; j < 4; ++j) acc[i][j] = (f32x4){0.f, 0.f, 0.f, 0.f};

    #pragma unroll
    for (int pass = 0; pass < 2; ++pass) {
        const unsigned short* Amat = pass ? Tb : Xb;
        const unsigned short* Wmat = pass ? W1T : W0T;
        for (int k0 = 0; k0 < K; k0 += 64) {
            if (pass != 0 || k0 != 0) __syncthreads();
            #pragma unroll
            for (int r = 0; r < 2; ++r) {
                int row = r * 32 + srow;
                int grow = row0 + row; if (grow > M - 1) grow = M - 1;
                uint4 v = *reinterpret_cast<const uint4*>(&Amat[(size_t)grow * K + k0 + scol]);
                *reinterpret_cast<uint4*>(&As[row * SA + scol]) = v;
            }
            #pragma unroll
            for (int r = 0; r < 8; ++r) {
                int row = r * 32 + srow;
                uint4 v = *reinterpret_cast<const uint4*>(&Wmat[(size_t)row * K + k0 + scol]);
                *reinterpret_cast<uint4*>(&Bs[row * SA + scol]) = v;
            }
            __syncthreads();

            #pragma unroll
            for (int kf = 0; kf < 2; ++kf) {
                const int koff = kf * 32 + quad * 8;
                bf16x8 a[4], b[4];
                #pragma unroll
                for (int mt = 0; mt < 4; ++mt)
                    a[mt] = *reinterpret_cast<const bf16x8*>(&As[(mt * 16 + l15) * SA + koff]);
                #pragma unroll
                for (int nt = 0; nt < 4; ++nt)
                    b[nt] = *reinterpret_cast<const bf16x8*>(
                        &Bs[(wave * 64 + nt * 16 + l15) * SA + koff]);
                #pragma unroll
                for (int mt = 0; mt < 4; ++mt)
                    #pragma unroll
                    for (int nt = 0; nt < 4; ++nt)
                        acc[mt][nt] = __builtin_amdgcn_mfma_f32_16x16x32_bf16(
                            a[mt], b[nt], acc[mt][nt], 0, 0, 0);
            }
        }
    }

    // epilogue: C/D layout col=lane&15, row=quad*4+reg
    #pragma unroll
    for (int mt = 0; mt < 4; ++mt) {
        #pragma unroll
        for (int r = 0; r < 4; ++r) {
            int m = row0 + mt * 16 + quad * 4 + r;
            if (m >= M) continue;
            #pragma unroll
            for (int nt = 0; nt < 4; ++nt) {
                int n = wave * 64 + nt * 16 + l15;
                float v = acc[mt][nt][r] + bias[n];
                if (RELU) v = fmaxf(v, 0.0f);
                if constexpr (sizeof(OutT) == 2)
                    out[(size_t)m * 256 + n] = (OutT)f2bf(v);
                else
                    out[(size_t)m * 256 + n] = (OutT)v;
            }
        }
    }
}

static inline size_t align_up(size_t v, size_t a) { return (v + a - 1) / a * a; }

extern "C" void kernel_launch(void* const* d_in, const int* in_sizes, int n_in,
                              void* d_out, int out_size, void* d_ws, size_t ws_size,
                              hipStream_t stream) {
    const float* x    = (const float*)d_in[0];
    const int*   ei   = (const int*)d_in[1];
    const float* W1_0 = (const float*)d_in[2];
    const float* W1_1 = (const float*)d_in[3];
    const float* b1   = (const float*)d_in[4];
    const float* W2_0 = (const float*)d_in[5];
    const float* W2_1 = (const float*)d_in[6];
    const float* b2   = (const float*)d_in[7];
    const float* W3_0 = (const float*)d_in[8];
    const float* W3_1 = (const float*)d_in[9];
    const float* b3   = (const float*)d_in[10];
    float* out = (float*)d_out;

    const int N = in_sizes[0] / 128;
    const int E = in_sizes[1] / 2;
    const int* src = ei;
    const int* dst = ei + E;

    typedef unsigned short u16;
    char* ws = (char*)d_ws;
    size_t off = 0;
    float* dinv   = (float*)(ws + off); off = align_up(off + (size_t)N * 4, 256);
    int*   cnt    = (int*)  (ws + off); off = align_up(off + (size_t)N * 4, 256);
    int*   cnt2   = (int*)  (ws + off); off = align_up(off + (size_t)N * 4, 256);
    size_t zero_end = off;                     // one memset covers dinv+cnt+cnt2
    int*   rowptr = (int*)  (ws + off); off = align_up(off + (size_t)(N + 1) * 4, 256);
    int*   part   = (int*)  (ws + off); off = align_up(off + 256 * 4, 256);
    int*   esrc   = (int*)  (ws + off); off = align_up(off + (size_t)E * 4, 256);
    float* ew     = (float*)(ws + off); off = align_up(off + (size_t)E * 4, 256);
    u16*   xb     = (u16*)  (ws + off); off = align_up(off + (size_t)N * 128 * 2, 256);
    u16*   txb    = (u16*)  (ws + off); off = align_up(off + (size_t)N * 256 * 2, 256);
    u16*   h1b    = (u16*)  (ws + off); off = align_up(off + (size_t)N * 256 * 2, 256);
    u16*   h2b    = (u16*)  (ws + off); off = align_up(off + (size_t)N * 256 * 2, 256);
    u16*   W10T   = (u16*)  (ws + off); off = align_up(off + (size_t)256 * 128 * 2, 256);
    u16*   W11T   = (u16*)  (ws + off); off = align_up(off + (size_t)256 * 128 * 2, 256);
    u16*   W20T   = (u16*)  (ws + off); off = align_up(off + (size_t)256 * 256 * 2, 256);
    u16*   W21T   = (u16*)  (ws + off); off = align_up(off + (size_t)256 * 256 * 2, 256);
    u16*   W30T   = (u16*)  (ws + off); off = align_up(off + (size_t)256 * 256 * 2, 256);
    u16*   W31T   = (u16*)  (ws + off); off = align_up(off + (size_t)256 * 256 * 2, 256);
    (void)ws_size;

    const int TB = 256;
    dim3 gE((E + TB - 1) / TB);
    const int NB = (N + 1023) / 1024;

    // ---- norm + CSR build ----
    hipMemsetAsync(dinv, 0, zero_end, stream);
    deg_cnt_kernel<<<gE, TB, 0, stream>>>(src, dst, dinv, cnt, E);
    scan_partial_dinv<<<NB, 256, 0, stream>>>(cnt, part, dinv, N);
    scan_small<<<1, 64, 0, stream>>>(part, NB, rowptr, N);
    scan_chunk<<<NB, 256, 0, stream>>>(cnt, part, rowptr, N);
    fill_kernel<<<gE, TB, 0, stream>>>(src, dst, dinv, rowptr, cnt2, esrc, ew, E);

    // ---- prep casts ----
    {
        long long n4 = (long long)N * 128 / 4;
        cast_x_kernel<<<(unsigned)((n4 + 255) / 256), TB, 0, stream>>>(x, xb, n4);
    }
    {
        TParams p;
        p.W[0] = W1_0; p.WT[0] = W10T; p.K[0] = 128;
        p.W[1] = W1_1; p.WT[1] = W11T; p.K[1] = 128;
        p.W[2] = W2_0; p.WT[2] = W20T; p.K[2] = 256;
        p.W[3] = W2_1; p.WT[3] = W21T; p.K[3] = 256;
        p.W[4] = W3_0; p.WT[4] = W30T; p.K[4] = 256;
        p.W[5] = W3_1; p.WT[5] = W31T; p.K[5] = 256;
        transpose_cast_all<<<dim3(8, 8, 6), TB, 0, stream>>>(p);
    }

    dim3 gemmGrid((N + 63) / 64);
    dim3 gatherGrid((N + 3) / 4);

    // ---- layer 1: F=128 ----
    gather_bf16<128><<<gatherGrid, TB, 0, stream>>>(rowptr, esrc, ew, xb, txb, N);
    gemm_mfma<128, true, u16><<<gemmGrid, TB, 0, stream>>>(xb, txb, W10T, W11T, b1, h1b, N);

    // ---- layer 2: F=256 ----
    gather_bf16<256><<<gatherGrid, TB, 0, stream>>>(rowptr, esrc, ew, h1b, txb, N);
    gemm_mfma<256, true, u16><<<gemmGrid, TB, 0, stream>>>(h1b, txb, W20T, W21T, b2, h2b, N);

    // ---- layer 3: F=256, no relu, fp32 out ----
    gather_bf16<256><<<gatherGrid, TB, 0, stream>>>(rowptr, esrc, ew, h2b, txb, N);
    gemm_mfma<256, false, float><<<gemmGrid, TB, 0, stream>>>(h2b, txb, W30T, W31T, b3, out, N);
}

// Round 8
// 329.021 us; speedup vs baseline: 1.7873x; 1.0742x over previous
//
#include <hip/hip_runtime.h>
#include <hip/hip_bf16.h>

// ---------------------------------------------------------------------------
// GraphChebNet: 3-layer ChebConv (K=2), N=50000, E=400000.
// Round 8: (1) prep merged into one kernel (deg/cnt atomics + x->bf16 cast +
// 6 weight transposes, grid-partitioned) -> 12 dispatches; (2) scan_small
// wave-parallel (was 49 serial global round-trips by one thread); (3) GEMM
// staging via global_load_lds(16B) with XOR-swizzled source columns (no LDS
// pad needed; reads stay at free 2-way bank aliasing); (4) gather: half-wave
// per node (32 lanes x 16B row segments) -> half the issue count, 2x rows in
// flight. CSR fill keeps the round-7 hazard-safe rowptr+atomic(cnt2) form.
// ---------------------------------------------------------------------------

typedef __attribute__((ext_vector_type(8))) short bf16x8;
typedef __attribute__((ext_vector_type(4))) float f32x4;

__device__ __forceinline__ float bf2f(unsigned int lo16) {
    unsigned int t = lo16 << 16;
    return __builtin_bit_cast(float, t);
}
__device__ __forceinline__ unsigned short f2bf(float f) {
    unsigned int u = __builtin_bit_cast(unsigned int, f);
    unsigned int r = (u + 0x7fffu + ((u >> 16) & 1u)) >> 16;   // RNE
    return (unsigned short)r;
}

// ---------------- fused prep: deg/cnt histograms + cast x + transpose W ----
struct PrepParams {
    const int* src;
    const int* dst;
    float* deg;
    int* cnt;
    int E;
    const float* x;
    unsigned short* xb;
    int gE;     // blocks for edge histogram
    int gC;     // blocks for x cast
    const float* W[6];
    unsigned short* WT[6];
    int K[6];
};

__global__ __launch_bounds__(256) void prep_kernel(PrepParams p) {
    __shared__ float t[32][33];
    int b = blockIdx.x;
    int tid = threadIdx.x;
    if (b < p.gE) {
        int e = b * 256 + tid;
        if (e < p.E) {
            int s = p.src[e], d = p.dst[e];
            if (s != d) atomicAdd(&p.deg[s], 1.0f);
            atomicAdd(&p.cnt[d], 1);
        }
        return;
    }
    b -= p.gE;
    if (b < p.gC) {
        long long i = (long long)b * 256 + tid;   // n4 elements exactly = gC*256
        float4 v = reinterpret_cast<const float4*>(p.x)[i];
        ushort4 o;
        o.x = f2bf(v.x); o.y = f2bf(v.y); o.z = f2bf(v.z); o.w = f2bf(v.w);
        reinterpret_cast<ushort4*>(p.xb)[i] = o;
        return;
    }
    b -= p.gC;                       // 0..383 : 6 matrices x 64 tiles
    int m = b >> 6;
    int rem = b & 63;
    int K = p.K[m];
    int kb = (rem & 7) * 32, nb = (rem >> 3) * 32;
    if (kb >= K) return;
    const float* W = p.W[m];
    unsigned short* WT = p.WT[m];
    int lx = tid & 31, ly = tid >> 5;   // 32 x 8
    #pragma unroll
    for (int i = 0; i < 32; i += 8)
        t[ly + i][lx] = W[(size_t)(kb + ly + i) * 256 + nb + lx];
    __syncthreads();
    #pragma unroll
    for (int i = 0; i < 32; i += 8)
        WT[(size_t)(nb + ly + i) * K + kb + lx] = f2bf(t[lx][ly + i]);
}

// ---------------- scan: partial sums + dinv ----------------
__global__ __launch_bounds__(256) void scan_partial_dinv(const int* __restrict__ cnt,
                                                         int* __restrict__ part,
                                                         float* __restrict__ deg, int N) {
    __shared__ int lds[256];
    int tid = threadIdx.x;
    int base = blockIdx.x * 1024 + tid * 4;
    int s = 0;
    #pragma unroll
    for (int i = 0; i < 4; ++i) {
        if (base + i < N) {
            s += cnt[base + i];
            float d = deg[base + i];
            deg[base + i] = (d > 0.0f) ? rsqrtf(d) : 0.0f;
        }
    }
    lds[tid] = s;
    __syncthreads();
    for (int off = 128; off > 0; off >>= 1) {
        if (tid < off) lds[tid] += lds[tid + off];
        __syncthreads();
    }
    if (tid == 0) part[blockIdx.x] = lds[0];
}

// wave-parallel exclusive scan of part[NB] (NB <= 64)
__global__ __launch_bounds__(64) void scan_small(int* __restrict__ part, int NB,
                                                 int* __restrict__ rowptr, int N) {
    int lane = threadIdx.x;
    int v = (lane < NB) ? part[lane] : 0;
    int inc = v;
    #pragma unroll
    for (int off = 1; off < 64; off <<= 1) {
        int t = __shfl_up(inc, off, 64);
        if (lane >= off) inc += t;
    }
    if (lane < NB) part[lane] = inc - v;   // exclusive
    if (lane == 63) rowptr[N] = inc;       // total (lanes past NB carry 0)
}

__global__ __launch_bounds__(256) void scan_chunk(const int* __restrict__ cnt,
                                                  const int* __restrict__ part,
                                                  int* __restrict__ rowptr, int N) {
    __shared__ int lds[256];
    int tid = threadIdx.x;
    int base = blockIdx.x * 1024 + tid * 4;
    int c[4];
    #pragma unroll
    for (int i = 0; i < 4; ++i) c[i] = (base + i < N) ? cnt[base + i] : 0;
    int ts = c[0] + c[1] + c[2] + c[3];
    lds[tid] = ts;
    __syncthreads();
    for (int off = 1; off < 256; off <<= 1) {
        int v = (tid >= off) ? lds[tid - off] : 0;
        __syncthreads();
        lds[tid] += v;
        __syncthreads();
    }
    int o = part[blockIdx.x] + lds[tid] - ts;
    #pragma unroll
    for (int i = 0; i < 4; ++i) {
        if (base + i < N) rowptr[base + i] = o;
        o += c[i];
    }
}

// CSR fill: slot = rowptr[d] + atomic rank in cnt2 (memset-0 by SDMA — the
// hazard-safe pattern from round 7; do NOT plain-store then atomic-RMW).
__global__ __launch_bounds__(256) void fill_kernel(const int* __restrict__ src,
                                                   const int* __restrict__ dst,
                                                   const float* __restrict__ dinv,
                                                   const int* __restrict__ rowptr,
                                                   int* __restrict__ cnt2,
                                                   int* __restrict__ esrc,
                                                   float* __restrict__ ew, int E) {
    int e = blockIdx.x * blockDim.x + threadIdx.x;
    if (e < E) {
        int s = src[e], d = dst[e];
        int pos = rowptr[d] + atomicAdd(&cnt2[d], 1);
        esrc[pos] = s;
        ew[pos] = (s != d) ? (-dinv[s] * dinv[d]) : 0.0f;
    }
}

// ---------------- gather: tx[n,:] = sum_e w_e * x[src_e,:] ----------------
// half-wave (32 lanes) per node; lane holds V=F/32 bf16 features; edge loop
// unrolled x4 -> 4 independent row loads in flight per half-wave.
template <int V> struct RowT;
template <> struct RowT<4> { using T = uint2; };
template <> struct RowT<8> { using T = uint4; };

__device__ __forceinline__ void fma_row(float* acc, uint2 u, float wv) {
    acc[0] += wv * bf2f(u.x & 0xffffu);
    acc[1] += wv * bf2f(u.x >> 16);
    acc[2] += wv * bf2f(u.y & 0xffffu);
    acc[3] += wv * bf2f(u.y >> 16);
}
__device__ __forceinline__ void fma_row(float* acc, uint4 u, float wv) {
    acc[0] += wv * bf2f(u.x & 0xffffu);
    acc[1] += wv * bf2f(u.x >> 16);
    acc[2] += wv * bf2f(u.y & 0xffffu);
    acc[3] += wv * bf2f(u.y >> 16);
    acc[4] += wv * bf2f(u.z & 0xffffu);
    acc[5] += wv * bf2f(u.z >> 16);
    acc[6] += wv * bf2f(u.w & 0xffffu);
    acc[7] += wv * bf2f(u.w >> 16);
}
__device__ __forceinline__ void pack_out(unsigned short* q, const float* acc, uint2*) {
    uint2 o;
    o.x = (unsigned int)f2bf(acc[0]) | ((unsigned int)f2bf(acc[1]) << 16);
    o.y = (unsigned int)f2bf(acc[2]) | ((unsigned int)f2bf(acc[3]) << 16);
    *reinterpret_cast<uint2*>(q) = o;
}
__device__ __forceinline__ void pack_out(unsigned short* q, const float* acc, uint4*) {
    uint4 o;
    o.x = (unsigned int)f2bf(acc[0]) | ((unsigned int)f2bf(acc[1]) << 16);
    o.y = (unsigned int)f2bf(acc[2]) | ((unsigned int)f2bf(acc[3]) << 16);
    o.z = (unsigned int)f2bf(acc[4]) | ((unsigned int)f2bf(acc[5]) << 16);
    o.w = (unsigned int)f2bf(acc[6]) | ((unsigned int)f2bf(acc[7]) << 16);
    *reinterpret_cast<uint4*>(q) = o;
}

template <int F>
__global__ __launch_bounds__(256) void gather_bf16(const int* __restrict__ rowptr,
                                                   const int* __restrict__ esrc,
                                                   const float* __restrict__ ew,
                                                   const unsigned short* __restrict__ xb,
                                                   unsigned short* __restrict__ txb,
                                                   int N) {
    constexpr int V = F / 32;   // 4 (F=128) or 8 (F=256)
    using T = typename RowT<V>::T;
    int half = threadIdx.x >> 5;     // 0..7
    int lane = threadIdx.x & 31;
    int n = blockIdx.x * 8 + half;
    if (n >= N) return;
    int beg = rowptr[n], end = rowptr[n + 1];
    float acc[V] = {};

    int k = beg;
    for (; k + 4 <= end; k += 4) {
        int s0 = esrc[k], s1 = esrc[k + 1], s2 = esrc[k + 2], s3 = esrc[k + 3];
        float w0 = ew[k], w1 = ew[k + 1], w2 = ew[k + 2], w3 = ew[k + 3];
        T r0 = *reinterpret_cast<const T*>(&xb[(size_t)s0 * F + lane * V]);
        T r1 = *reinterpret_cast<const T*>(&xb[(size_t)s1 * F + lane * V]);
        T r2 = *reinterpret_cast<const T*>(&xb[(size_t)s2 * F + lane * V]);
        T r3 = *reinterpret_cast<const T*>(&xb[(size_t)s3 * F + lane * V]);
        fma_row(acc, r0, w0);
        fma_row(acc, r1, w1);
        fma_row(acc, r2, w2);
        fma_row(acc, r3, w3);
    }
    for (; k < end; ++k) {
        int s = esrc[k];
        float wv = ew[k];
        T r = *reinterpret_cast<const T*>(&xb[(size_t)s * F + lane * V]);
        fma_row(acc, r, wv);
    }

    pack_out(&txb[(size_t)n * F + lane * V], acc, (T*)nullptr);
}

// ---------------- MFMA GEMM, BN=256, global_load_lds staging ----------------
// out[M,256] = relu?( Xb[M,K]@W0 + Tb[M,K]@W1 + b ), weights as WT[n][k] bf16.
// LDS rows are 64 shorts (128B, no pad). Source columns XOR-swizzled in 16B
// units: LDS unit u of row R holds global unit u^(R&7); reader fetches unit
// g at LDS unit g^(l15&7) -> 2-way bank aliasing only (free).
template <int K, bool RELU, typename OutT>
__global__ __launch_bounds__(256, 3) void gemm_mfma(const unsigned short* __restrict__ Xb,
                                                    const unsigned short* __restrict__ Tb,
                                                    const unsigned short* __restrict__ W0T,
                                                    const unsigned short* __restrict__ W1T,
                                                    const float* __restrict__ bias,
                                                    OutT* __restrict__ out, int M) {
    __shared__ unsigned short As[64 * 64];
    __shared__ unsigned short Bs[256 * 64];

    const int tid = threadIdx.x;
    const int wave = tid >> 6;
    const int lane = tid & 63;
    const int l15 = lane & 15;
    const int quad = lane >> 4;
    const int row0 = blockIdx.x * 64;
    // staging: lane l of wave w covers row (base + w*8 + (l>>3)), 16B unit (l&7),
    // swizzled source unit = (l&7) ^ ((l>>3)&7)  [row&7 == (l>>3)&7]
    const int swz = ((lane & 7) ^ ((lane >> 3) & 7)) * 8;   // shorts

    f32x4 acc[4][4];
    #pragma unroll
    for (int i = 0; i < 4; ++i)
        #pragma unroll
        for (int j = 0; j < 4; ++j) acc[i][j] = (f32x4){0.f, 0.f, 0.f, 0.f};

    typedef const __attribute__((address_space(1))) void gvoid;
    typedef __attribute__((address_space(3))) void lvoid;

    #pragma unroll
    for (int pass = 0; pass < 2; ++pass) {
        const unsigned short* Amat = pass ? Tb : Xb;
        const unsigned short* Wmat = pass ? W1T : W0T;
        for (int k0 = 0; k0 < K; k0 += 64) {
            if (pass != 0 || k0 != 0) __syncthreads();
            #pragma unroll
            for (int r = 0; r < 2; ++r) {
                int grow = row0 + r * 32 + wave * 8 + (lane >> 3);
                if (grow > M - 1) grow = M - 1;
                const unsigned short* gp = &Amat[(size_t)grow * K + k0 + swz];
                __builtin_amdgcn_global_load_lds((gvoid*)gp,
                    (lvoid*)&As[(r * 32 + wave * 8) * 64], 16, 0, 0);
            }
            #pragma unroll
            for (int r = 0; r < 8; ++r) {
                int brow = r * 32 + wave * 8 + (lane >> 3);
                const unsigned short* gp = &Wmat[(size_t)brow * K + k0 + swz];
                __builtin_amdgcn_global_load_lds((gvoid*)gp,
                    (lvoid*)&Bs[(r * 32 + wave * 8) * 64], 16, 0, 0);
            }
            __syncthreads();

            #pragma unroll
            for (int kf = 0; kf < 2; ++kf) {
                const int col = (((kf * 4 + quad) ^ (l15 & 7)) * 8);
                bf16x8 a[4], b[4];
                #pragma unroll
                for (int mt = 0; mt < 4; ++mt)
                    a[mt] = *reinterpret_cast<const bf16x8*>(&As[(mt * 16 + l15) * 64 + col]);
                #pragma unroll
                for (int nt = 0; nt < 4; ++nt)
                    b[nt] = *reinterpret_cast<const bf16x8*>(
                        &Bs[(wave * 64 + nt * 16 + l15) * 64 + col]);
                #pragma unroll
                for (int mt = 0; mt < 4; ++mt)
                    #pragma unroll
                    for (int nt = 0; nt < 4; ++nt)
                        acc[mt][nt] = __builtin_amdgcn_mfma_f32_16x16x32_bf16(
                            a[mt], b[nt], acc[mt][nt], 0, 0, 0);
            }
        }
    }

    // epilogue: C/D layout col=lane&15, row=quad*4+reg
    #pragma unroll
    for (int mt = 0; mt < 4; ++mt) {
        #pragma unroll
        for (int r = 0; r < 4; ++r) {
            int m = row0 + mt * 16 + quad * 4 + r;
            if (m >= M) continue;
            #pragma unroll
            for (int nt = 0; nt < 4; ++nt) {
                int n = wave * 64 + nt * 16 + l15;
                float v = acc[mt][nt][r] + bias[n];
                if (RELU) v = fmaxf(v, 0.0f);
                if constexpr (sizeof(OutT) == 2)
                    out[(size_t)m * 256 + n] = (OutT)f2bf(v);
                else
                    out[(size_t)m * 256 + n] = (OutT)v;
            }
        }
    }
}

static inline size_t align_up(size_t v, size_t a) { return (v + a - 1) / a * a; }

extern "C" void kernel_launch(void* const* d_in, const int* in_sizes, int n_in,
                              void* d_out, int out_size, void* d_ws, size_t ws_size,
                              hipStream_t stream) {
    const float* x    = (const float*)d_in[0];
    const int*   ei   = (const int*)d_in[1];
    const float* W1_0 = (const float*)d_in[2];
    const float* W1_1 = (const float*)d_in[3];
    const float* b1   = (const float*)d_in[4];
    const float* W2_0 = (const float*)d_in[5];
    const float* W2_1 = (const float*)d_in[6];
    const float* b2   = (const float*)d_in[7];
    const float* W3_0 = (const float*)d_in[8];
    const float* W3_1 = (const float*)d_in[9];
    const float* b3   = (const float*)d_in[10];
    float* out = (float*)d_out;

    const int N = in_sizes[0] / 128;
    const int E = in_sizes[1] / 2;
    const int* src = ei;
    const int* dst = ei + E;

    typedef unsigned short u16;
    char* ws = (char*)d_ws;
    size_t off = 0;
    float* dinv   = (float*)(ws + off); off = align_up(off + (size_t)N * 4, 256);
    int*   cnt    = (int*)  (ws + off); off = align_up(off + (size_t)N * 4, 256);
    int*   cnt2   = (int*)  (ws + off); off = align_up(off + (size_t)N * 4, 256);
    size_t zero_end = off;                     // one memset covers dinv+cnt+cnt2
    int*   rowptr = (int*)  (ws + off); off = align_up(off + (size_t)(N + 1) * 4, 256);
    int*   part   = (int*)  (ws + off); off = align_up(off + 256 * 4, 256);
    int*   esrc   = (int*)  (ws + off); off = align_up(off + (size_t)E * 4, 256);
    float* ew     = (float*)(ws + off); off = align_up(off + (size_t)E * 4, 256);
    u16*   xb     = (u16*)  (ws + off); off = align_up(off + (size_t)N * 128 * 2, 256);
    u16*   txb    = (u16*)  (ws + off); off = align_up(off + (size_t)N * 256 * 2, 256);
    u16*   h1b    = (u16*)  (ws + off); off = align_up(off + (size_t)N * 256 * 2, 256);
    u16*   h2b    = (u16*)  (ws + off); off = align_up(off + (size_t)N * 256 * 2, 256);
    u16*   W10T   = (u16*)  (ws + off); off = align_up(off + (size_t)256 * 128 * 2, 256);
    u16*   W11T   = (u16*)  (ws + off); off = align_up(off + (size_t)256 * 128 * 2, 256);
    u16*   W20T   = (u16*)  (ws + off); off = align_up(off + (size_t)256 * 256 * 2, 256);
    u16*   W21T   = (u16*)  (ws + off); off = align_up(off + (size_t)256 * 256 * 2, 256);
    u16*   W30T   = (u16*)  (ws + off); off = align_up(off + (size_t)256 * 256 * 2, 256);
    u16*   W31T   = (u16*)  (ws + off); off = align_up(off + (size_t)256 * 256 * 2, 256);
    (void)ws_size;

    const int TB = 256;
    const int gE = (E + TB - 1) / TB;                       // 1563
    const int gC = (int)(((long long)N * 128 / 4) / 256);   // 6250 (exact)
    const int NB = (N + 1023) / 1024;                       // 49

    // ---- init ----
    hipMemsetAsync(dinv, 0, zero_end, stream);

    // ---- fused prep: histograms + cast x + transpose weights ----
    {
        PrepParams p;
        p.src = src; p.dst = dst; p.deg = dinv; p.cnt = cnt; p.E = E;
        p.x = x; p.xb = xb; p.gE = gE; p.gC = gC;
        p.W[0] = W1_0; p.WT[0] = W10T; p.K[0] = 128;
        p.W[1] = W1_1; p.WT[1] = W11T; p.K[1] = 128;
        p.W[2] = W2_0; p.WT[2] = W20T; p.K[2] = 256;
        p.W[3] = W2_1; p.WT[3] = W21T; p.K[3] = 256;
        p.W[4] = W3_0; p.WT[4] = W30T; p.K[4] = 256;
        p.W[5] = W3_1; p.WT[5] = W31T; p.K[5] = 256;
        prep_kernel<<<gE + gC + 384, TB, 0, stream>>>(p);
    }

    // ---- CSR build ----
    scan_partial_dinv<<<NB, 256, 0, stream>>>(cnt, part, dinv, N);
    scan_small<<<1, 64, 0, stream>>>(part, NB, rowptr, N);
    scan_chunk<<<NB, 256, 0, stream>>>(cnt, part, rowptr, N);
    fill_kernel<<<(E + TB - 1) / TB, TB, 0, stream>>>(src, dst, dinv, rowptr, cnt2,
                                                      esrc, ew, E);

    dim3 gemmGrid((N + 63) / 64);
    dim3 gatherGrid((N + 7) / 8);

    // ---- layer 1: F=128 ----
    gather_bf16<128><<<gatherGrid, TB, 0, stream>>>(rowptr, esrc, ew, xb, txb, N);
    gemm_mfma<128, true, u16><<<gemmGrid, TB, 0, stream>>>(xb, txb, W10T, W11T, b1, h1b, N);

    // ---- layer 2: F=256 ----
    gather_bf16<256><<<gatherGrid, TB, 0, stream>>>(rowptr, esrc, ew, h1b, txb, N);
    gemm_mfma<256, true, u16><<<gemmGrid, TB, 0, stream>>>(h1b, txb, W20T, W21T, b2, h2b, N);

    // ---- layer 3: F=256, no relu, fp32 out ----
    gather_bf16<256><<<gatherGrid, TB, 0, stream>>>(rowptr, esrc, ew, h2b, txb, N);
    gemm_mfma<256, false, float><<<gemmGrid, TB, 0, stream>>>(h2b, txb, W30T, W31T, b3, out, N);
}